// Round 6
// baseline (787.659 us; speedup 1.0000x reference)
//
#include <hip/hip_runtime.h>
#include <hip/hip_bf16.h>

// Problem constants
#define D_      256
#define NH_     8
#define HD_     32
#define NL_     3
#define NP_4    4
#define BS_     32
#define LQ_     300
#define LV_     8400
#define DFF_    1024
#define NTOK    (BS_ * LQ_)        // 9600
#define NVAL    (BS_ * LV_)        // 268800

typedef __attribute__((ext_vector_type(8))) short bf16x8;
typedef __attribute__((ext_vector_type(4))) float f32x4;

__device__ inline unsigned short f2bf(float x) {
    union { float f; unsigned u; } v; v.f = x;
    unsigned r = v.u + 0x7FFFu + ((v.u >> 16) & 1u);
    return (unsigned short)(r >> 16);
}
__device__ inline float bf2f(unsigned short x) {
    union { unsigned u; float f; } v; v.u = ((unsigned)x) << 16;
    return v.f;
}

// ---------------------------------------------------------------------------
// Weight transpose+convert: Wt[n][k] = bf16(W[k][n]). 10 weights, one launch.
// ---------------------------------------------------------------------------
struct TrDesc { const float* W; unsigned short* Wt; int K; int N; };
struct TrPack { TrDesc d[10]; };

__global__ __launch_bounds__(256)
void tr_kernel(TrPack p) {
    TrDesc d = p.d[blockIdx.z];
    const int n0 = blockIdx.x * 32, k0 = blockIdx.y * 32;
    if (n0 >= d.N || k0 >= d.K) return;
    __shared__ float t[32][33];
    const int tx = threadIdx.x & 31, ty = threadIdx.x >> 5;
    #pragma unroll
    for (int i = 0; i < 4; ++i) {
        int k = k0 + ty + i * 8, n = n0 + tx;
        t[ty + i * 8][tx] = (k < d.K && n < d.N) ? d.W[(size_t)k * d.N + n] : 0.f;
    }
    __syncthreads();
    #pragma unroll
    for (int i = 0; i < 4; ++i) {
        int n = n0 + ty + i * 8, k = k0 + tx;
        if (n < d.N && k < d.K) d.Wt[(size_t)n * d.K + k] = f2bf(t[tx][ty + i * 8]);
    }
}

// ---------------------------------------------------------------------------
// Chunked whole-K LDS GEMM. KC=128 (NC=2): round-2/5 post-mortems proved the
// phase structure (not occupancy) binds; this config is the measured best.
// PF=1 (NC==2, AMODE==0 only): T14 async-STAGE split — after the chunk-0
// barrier, issue chunk-1 global loads into REGISTERS, compute chunk 0 (loads
// in flight under the MFMAs), then cvt+ds_write chunk 1 after the barrier.
// 3 barriers total, chunk-1 HBM latency hidden. +64 VGPR (52 -> ~116 < 128).
// AMODE: 0 = f32 A, 2 = bf16 A. CMODE: 0 f32, 2 bf16, 3 bf16+relu.
// ---------------------------------------------------------------------------
template <int ROWS, int COLS, int KK, int KC, int WR, int WC, int AMODE, int CMODE, int PF>
__global__ __launch_bounds__(256, 4)
void gemm_os(const void* __restrict__ Ain,
             const unsigned short* __restrict__ Wt, const float* __restrict__ bias,
             void* __restrict__ Cout, int M, int N) {
    constexpr int LDK = KC + 8;
    constexpr int NC = KK / KC;
    constexpr int KS = KC / 32;
    constexpr int WROWS = ROWS / WR, WCOLS = COLS / WC;
    constexpr int RT = WROWS / 16, TC = WCOLS / 16;
    __shared__ unsigned short Alds[ROWS * LDK];
    __shared__ unsigned short Blds[COLS * LDK];

    const int tid = threadIdx.x, lane = tid & 63, w = tid >> 6;
    const int quad = lane >> 4, l16 = lane & 15;
    const int wr = w / WC, wc = w % WC;
    const int rowBase = blockIdx.y * ROWS;
    const int colBase = blockIdx.x * COLS;

    f32x4 acc[RT][TC];
    #pragma unroll
    for (int rt = 0; rt < RT; ++rt)
        #pragma unroll
        for (int j = 0; j < TC; ++j)
            #pragma unroll
            for (int r = 0; r < 4; ++r) acc[rt][j][r] = 0.f;

    auto stageA = [&](int ch) {
        if (AMODE == 2) {
            constexpr int CNT2 = ROWS * KC / 2048;
            #pragma unroll
            for (int i = 0; i < CNT2; ++i) {
                int idx = i * 256 + tid;
                int row = idx / (KC / 8), kofs = (idx % (KC / 8)) * 8;
                int4 v = *(const int4*)((const unsigned short*)Ain +
                          (size_t)(rowBase + row) * KK + ch * KC + kofs);
                *(int4*)&Alds[row * LDK + kofs] = v;
            }
        } else {
            constexpr int CNT = ROWS * KC / 1024;
            #pragma unroll
            for (int i = 0; i < CNT; ++i) {
                int idx = i * 256 + tid;
                int row = idx / (KC / 4), kofs = (idx % (KC / 4)) * 4;
                size_t gg = (size_t)(rowBase + row) * KK + ch * KC + kofs;
                float4 a = *(const float4*)((const float*)Ain + gg);
                ushort4 s4;
                s4.x = f2bf(a.x); s4.y = f2bf(a.y);
                s4.z = f2bf(a.z); s4.w = f2bf(a.w);
                *(ushort4*)&Alds[row * LDK + kofs] = s4;
            }
        }
    };
    auto stageB = [&](int ch) {
        constexpr int CNT = COLS * KC / 2048;
        #pragma unroll
        for (int i = 0; i < CNT; ++i) {
            int idx = i * 256 + tid;
            int col = idx / (KC / 8), kofs = (idx % (KC / 8)) * 8;
            int4 v = *(const int4*)(Wt + (size_t)(colBase + col) * KK + ch * KC + kofs);
            *(int4*)&Blds[col * LDK + kofs] = v;
        }
    };
    auto computeChunk = [&]() {
        #pragma unroll
        for (int s = 0; s < KS; ++s) {
            bf16x8 af[RT], bfr[TC];
            #pragma unroll
            for (int rt = 0; rt < RT; ++rt)
                af[rt] = *(const bf16x8*)&Alds[(wr * WROWS + rt * 16 + l16) * LDK + s * 32 + quad * 8];
            #pragma unroll
            for (int j = 0; j < TC; ++j)
                bfr[j] = *(const bf16x8*)&Blds[(wc * WCOLS + j * 16 + l16) * LDK + s * 32 + quad * 8];
            #pragma unroll
            for (int rt = 0; rt < RT; ++rt)
                #pragma unroll
                for (int j = 0; j < TC; ++j)
                    acc[rt][j] = __builtin_amdgcn_mfma_f32_16x16x32_bf16(af[rt], bfr[j], acc[rt][j], 0, 0, 0);
        }
    };

    if constexpr (PF && NC == 2 && AMODE == 0) {
        constexpr int CNTA = ROWS * KC / 1024;   // float4/thread of chunk 1
        constexpr int CNTB = COLS * KC / 2048;   // int4/thread of chunk 1
        stageA(0); stageB(0);
        __syncthreads();
        // issue chunk-1 global loads (latency hides under chunk-0 MFMAs)
        float4 pa[CNTA]; int4 pb[CNTB];
        #pragma unroll
        for (int i = 0; i < CNTA; ++i) {
            int idx = i * 256 + tid;
            int row = idx / (KC / 4), kofs = (idx % (KC / 4)) * 4;
            pa[i] = *(const float4*)((const float*)Ain +
                     (size_t)(rowBase + row) * KK + KC + kofs);
        }
        #pragma unroll
        for (int i = 0; i < CNTB; ++i) {
            int idx = i * 256 + tid;
            int col = idx / (KC / 8), kofs = (idx % (KC / 8)) * 8;
            pb[i] = *(const int4*)(Wt + (size_t)(colBase + col) * KK + KC + kofs);
        }
        computeChunk();
        __syncthreads();
        // write chunk 1 from registers
        #pragma unroll
        for (int i = 0; i < CNTA; ++i) {
            int idx = i * 256 + tid;
            int row = idx / (KC / 4), kofs = (idx % (KC / 4)) * 4;
            ushort4 s4;
            s4.x = f2bf(pa[i].x); s4.y = f2bf(pa[i].y);
            s4.z = f2bf(pa[i].z); s4.w = f2bf(pa[i].w);
            *(ushort4*)&Alds[row * LDK + kofs] = s4;
        }
        #pragma unroll
        for (int i = 0; i < CNTB; ++i) {
            int idx = i * 256 + tid;
            int col = idx / (KC / 8), kofs = (idx % (KC / 8)) * 8;
            *(int4*)&Blds[col * LDK + kofs] = pb[i];
        }
        __syncthreads();
        computeChunk();
    } else {
        for (int ch = 0; ch < NC; ++ch) {
            if (NC > 1 && ch > 0) __syncthreads();
            stageA(ch); stageB(ch);
            __syncthreads();
            computeChunk();
        }
    }

    // ---- epilogue ----
    #pragma unroll
    for (int rt = 0; rt < RT; ++rt) {
        #pragma unroll
        for (int j = 0; j < TC; ++j) {
            int col = colBase + wc * WCOLS + j * 16 + l16;
            float bb = bias[col];
            #pragma unroll
            for (int r = 0; r < 4; ++r) {
                int row = rowBase + wr * WROWS + rt * 16 + quad * 4 + r;
                float c = acc[rt][j][r] + bb;
                if (CMODE == 3) c = fmaxf(c, 0.f);
                if (CMODE >= 2)
                    ((unsigned short*)Cout)[(size_t)row * N + col] = f2bf(c);
                else
                    ((float*)Cout)[(size_t)row * N + col] = c;
            }
        }
    }
}

// ---------------------------------------------------------------------------
// Batched GEMM: blockIdx.z selects an independent sub-problem (Q/K/V in one
// launch; off+awl in one launch). A is f32 with optional fused A2 add.
// ---------------------------------------------------------------------------
struct GDesc { const float* Ain; const float* A2; const unsigned short* Wt;
               const float* bias; void* Cout; int N; };
struct GPack3 { GDesc d[3]; };

template <int ROWS, int COLS, int KK, int KC, int WR, int WC, int CMODE>
__global__ __launch_bounds__(256, 4)
void gemm_osb(GPack3 pk) {
    constexpr int LDK = KC + 8;
    constexpr int NC = KK / KC;
    constexpr int KS = KC / 32;
    constexpr int WROWS = ROWS / WR, WCOLS = COLS / WC;
    constexpr int RT = WROWS / 16, TC = WCOLS / 16;
    __shared__ unsigned short Alds[ROWS * LDK];
    __shared__ unsigned short Blds[COLS * LDK];

    GDesc g = pk.d[blockIdx.z];
    const int colBase = blockIdx.x * COLS;
    if (colBase >= g.N) return;
    const int tid = threadIdx.x, lane = tid & 63, w = tid >> 6;
    const int quad = lane >> 4, l16 = lane & 15;
    const int wr = w / WC, wc = w % WC;
    const int rowBase = blockIdx.y * ROWS;

    f32x4 acc[RT][TC];
    #pragma unroll
    for (int rt = 0; rt < RT; ++rt)
        #pragma unroll
        for (int j = 0; j < TC; ++j)
            #pragma unroll
            for (int r = 0; r < 4; ++r) acc[rt][j][r] = 0.f;

    for (int ch = 0; ch < NC; ++ch) {
        if (NC > 1 && ch > 0) __syncthreads();
        {
            constexpr int CNT = ROWS * KC / 1024;
            #pragma unroll
            for (int i = 0; i < CNT; ++i) {
                int idx = i * 256 + tid;
                int row = idx / (KC / 4), kofs = (idx % (KC / 4)) * 4;
                size_t gg = (size_t)(rowBase + row) * KK + ch * KC + kofs;
                float4 a = *(const float4*)(g.Ain + gg);
                if (g.A2) {
                    float4 b = *(const float4*)(g.A2 + gg);
                    a.x += b.x; a.y += b.y; a.z += b.z; a.w += b.w;
                }
                ushort4 s4;
                s4.x = f2bf(a.x); s4.y = f2bf(a.y);
                s4.z = f2bf(a.z); s4.w = f2bf(a.w);
                *(ushort4*)&Alds[row * LDK + kofs] = s4;
            }
        }
        {
            constexpr int CNT = COLS * KC / 2048;
            #pragma unroll
            for (int i = 0; i < CNT; ++i) {
                int idx = i * 256 + tid;
                int col = idx / (KC / 8), kofs = (idx % (KC / 8)) * 8;
                int4 v = *(const int4*)(g.Wt + (size_t)(colBase + col) * KK + ch * KC + kofs);
                *(int4*)&Blds[col * LDK + kofs] = v;
            }
        }
        __syncthreads();

        #pragma unroll
        for (int s = 0; s < KS; ++s) {
            bf16x8 af[RT], bfr[TC];
            #pragma unroll
            for (int rt = 0; rt < RT; ++rt)
                af[rt] = *(const bf16x8*)&Alds[(wr * WROWS + rt * 16 + l16) * LDK + s * 32 + quad * 8];
            #pragma unroll
            for (int j = 0; j < TC; ++j)
                bfr[j] = *(const bf16x8*)&Blds[(wc * WCOLS + j * 16 + l16) * LDK + s * 32 + quad * 8];
            #pragma unroll
            for (int rt = 0; rt < RT; ++rt)
                #pragma unroll
                for (int j = 0; j < TC; ++j)
                    acc[rt][j] = __builtin_amdgcn_mfma_f32_16x16x32_bf16(af[rt], bfr[j], acc[rt][j], 0, 0, 0);
        }
    }

    #pragma unroll
    for (int rt = 0; rt < RT; ++rt) {
        #pragma unroll
        for (int j = 0; j < TC; ++j) {
            int col = colBase + wc * WCOLS + j * 16 + l16;
            float bb = g.bias[col];
            #pragma unroll
            for (int r = 0; r < 4; ++r) {
                int row = rowBase + wr * WROWS + rt * 16 + quad * 4 + r;
                float c = acc[rt][j][r] + bb;
                if (CMODE >= 2)
                    ((unsigned short*)g.Cout)[(size_t)row * g.N + col] = f2bf(c);
                else
                    ((float*)g.Cout)[(size_t)row * g.N + col] = c;
            }
        }
    }
}

// ---------------------------------------------------------------------------
// GEMM (bf16 A, full-row COLS=256) with fused residual-add + LayerNorm.
// out = LN(xres + A@Wt + bias) * lng + lnb.
// ---------------------------------------------------------------------------
template <int KK, int KC>
__global__ __launch_bounds__(256)
void gemm_ln(const unsigned short* __restrict__ Ain,
             const unsigned short* __restrict__ Wt, const float* __restrict__ bias,
             const float* __restrict__ xres, const float* __restrict__ lng,
             const float* __restrict__ lnb, float* __restrict__ Cout) {
    constexpr int ROWS = 32, COLS = 256;
    constexpr int LDK = KC + 8;
    constexpr int NC = KK / KC;
    constexpr int KS = KC / 32;
    constexpr int RT = 2, TC = 4;
    __shared__ unsigned short Alds[ROWS * LDK];
    __shared__ unsigned short Blds[COLS * LDK];
    __shared__ float redS[4][32];
    __shared__ float redQ[4][32];

    const int tid = threadIdx.x, lane = tid & 63, w = tid >> 6;
    const int quad = lane >> 4, l16 = lane & 15;
    const int wc = w;
    const int rowBase = blockIdx.x * ROWS;

    f32x4 acc[RT][TC];
    #pragma unroll
    for (int rt = 0; rt < RT; ++rt)
        #pragma unroll
        for (int j = 0; j < TC; ++j)
            #pragma unroll
            for (int r = 0; r < 4; ++r) acc[rt][j][r] = 0.f;

    for (int ch = 0; ch < NC; ++ch) {
        if (NC > 1 && ch > 0) __syncthreads();
        {
            constexpr int CNT2 = ROWS * KC / 2048;
            #pragma unroll
            for (int i = 0; i < CNT2; ++i) {
                int idx = i * 256 + tid;
                int row = idx / (KC / 8), kofs = (idx % (KC / 8)) * 8;
                int4 v = *(const int4*)(Ain + (size_t)(rowBase + row) * KK + ch * KC + kofs);
                *(int4*)&Alds[row * LDK + kofs] = v;
            }
        }
        {
            constexpr int CNT = COLS * KC / 2048;
            #pragma unroll
            for (int i = 0; i < CNT; ++i) {
                int idx = i * 256 + tid;
                int col = idx / (KC / 8), kofs = (idx % (KC / 8)) * 8;
                int4 v = *(const int4*)(Wt + (size_t)col * KK + ch * KC + kofs);
                *(int4*)&Blds[col * LDK + kofs] = v;
            }
        }
        __syncthreads();

        #pragma unroll
        for (int s = 0; s < KS; ++s) {
            bf16x8 af[RT], bfr[TC];
            #pragma unroll
            for (int rt = 0; rt < RT; ++rt)
                af[rt] = *(const bf16x8*)&Alds[(rt * 16 + l16) * LDK + s * 32 + quad * 8];
            #pragma unroll
            for (int j = 0; j < TC; ++j)
                bfr[j] = *(const bf16x8*)&Blds[(wc * 64 + j * 16 + l16) * LDK + s * 32 + quad * 8];
            #pragma unroll
            for (int rt = 0; rt < RT; ++rt)
                #pragma unroll
                for (int j = 0; j < TC; ++j)
                    acc[rt][j] = __builtin_amdgcn_mfma_f32_16x16x32_bf16(af[rt], bfr[j], acc[rt][j], 0, 0, 0);
        }
    }

    float p[RT][4], q[RT][4];
    #pragma unroll
    for (int rt = 0; rt < RT; ++rt)
        #pragma unroll
        for (int r = 0; r < 4; ++r) { p[rt][r] = 0.f; q[rt][r] = 0.f; }

    #pragma unroll
    for (int rt = 0; rt < RT; ++rt) {
        #pragma unroll
        for (int j = 0; j < TC; ++j) {
            int col = wc * 64 + j * 16 + l16;
            float bb = bias[col];
            #pragma unroll
            for (int r = 0; r < 4; ++r) {
                int row = rowBase + rt * 16 + quad * 4 + r;
                float v = acc[rt][j][r] + bb + xres[(size_t)row * 256 + col];
                acc[rt][j][r] = v;
                p[rt][r] += v;
                q[rt][r] += v * v;
            }
        }
    }
    #pragma unroll
    for (int rt = 0; rt < RT; ++rt)
        #pragma unroll
        for (int r = 0; r < 4; ++r)
            #pragma unroll
            for (int off = 1; off < 16; off <<= 1) {
                p[rt][r] += __shfl_xor(p[rt][r], off);
                q[rt][r] += __shfl_xor(q[rt][r], off);
            }
    if (l16 == 0) {
        #pragma unroll
        for (int rt = 0; rt < RT; ++rt)
            #pragma unroll
            for (int r = 0; r < 4; ++r) {
                redS[w][rt * 16 + quad * 4 + r] = p[rt][r];
                redQ[w][rt * 16 + quad * 4 + r] = q[rt][r];
            }
    }
    __syncthreads();
    #pragma unroll
    for (int rt = 0; rt < RT; ++rt) {
        #pragma unroll
        for (int r = 0; r < 4; ++r) {
            int ridx = rt * 16 + quad * 4 + r;
            float s  = redS[0][ridx] + redS[1][ridx] + redS[2][ridx] + redS[3][ridx];
            float ss = redQ[0][ridx] + redQ[1][ridx] + redQ[2][ridx] + redQ[3][ridx];
            float mean = s * (1.0f / 256.0f);
            float var  = ss * (1.0f / 256.0f) - mean * mean;
            float inv  = rsqrtf(var + 1e-5f);
            int row = rowBase + ridx;
            #pragma unroll
            for (int j = 0; j < TC; ++j) {
                int col = wc * 64 + j * 16 + l16;
                Cout[(size_t)row * 256 + col] =
                    (acc[rt][j][r] - mean) * inv * lng[col] + lnb[col];
            }
        }
    }
}

// ---------------------------------------------------------------------------
// Flash-style MFMA self-attention. Block = (b, h, half); 512 blocks.
// ---------------------------------------------------------------------------
#define PS_STRIDE 344
__global__ __launch_bounds__(256)
void attn_mfma(const unsigned short* __restrict__ qh,
               const unsigned short* __restrict__ kh,
               const unsigned short* __restrict__ vh,
               unsigned short* __restrict__ out) {
    __shared__ unsigned short Ps[4 * 16 * PS_STRIDE];
    __shared__ unsigned short Vs[32 * PS_STRIDE];
    const int tid = threadIdx.x;
    const int bh = blockIdx.x >> 1, half_ = blockIdx.x & 1;
    const int b = bh >> 3, h = bh & 7;
    const int w = tid >> 6, lane = tid & 63;
    const int quad = lane >> 4, l16 = lane & 15;

    for (int i = tid; i < 4 * 16 * PS_STRIDE / 2; i += 256) ((unsigned*)Ps)[i] = 0u;

    const size_t hbase = ((size_t)b * LQ_) * D_ + h * HD_;
    for (int it = 0; it < 10; ++it) {
        int chunk = tid + 256 * it;
        int key = chunk >> 3, cc = (chunk & 7) * 4;
        ushort4 v = make_ushort4(0, 0, 0, 0);
        if (key < LQ_) v = *(const ushort4*)(vh + hbase + (size_t)key * D_ + cc);
        Vs[(cc + 0) * PS_STRIDE + key] = v.x;
        Vs[(cc + 1) * PS_STRIDE + key] = v.y;
        Vs[(cc + 2) * PS_STRIDE + key] = v.z;
        Vs[(cc + 3) * PS_STRIDE + key] = v.w;
    }
    __syncthreads();

    const unsigned short* qb = qh + hbase;
    const unsigned short* kb = kh + hbase;
    const float scale = 0.17677669529663687f;

    for (int qt = 10 * half_ + w; qt < 10 * half_ + 10 && qt < 19; qt += 4) {
        int rowq = qt * 16 + l16; if (rowq > LQ_ - 1) rowq = LQ_ - 1;
        bf16x8 aq = *(const bf16x8*)(qb + (size_t)rowq * D_ + quad * 8);

        f32x4 S[19];
        #pragma unroll
        for (int kt = 0; kt < 19; ++kt) {
            int rowk = kt * 16 + l16; if (rowk > LQ_ - 1) rowk = LQ_ - 1;
            bf16x8 bk = *(const bf16x8*)(kb + (size_t)rowk * D_ + quad * 8);
            f32x4 z; z[0] = z[1] = z[2] = z[3] = 0.f;
            S[kt] = __builtin_amdgcn_mfma_f32_16x16x32_bf16(aq, bk, z, 0, 0, 0);
        }
        float mrow[4] = {-1e30f, -1e30f, -1e30f, -1e30f};
        #pragma unroll
        for (int kt = 0; kt < 19; ++kt) {
            bool masked = (kt == 18) && (l16 >= 12);
            #pragma unroll
            for (int r = 0; r < 4; ++r) {
                float s = masked ? -1e30f : S[kt][r] * scale;
                S[kt][r] = s;
                mrow[r] = fmaxf(mrow[r], s);
            }
        }
        #pragma unroll
        for (int r = 0; r < 4; ++r)
            #pragma unroll
            for (int off = 1; off < 16; off <<= 1)
                mrow[r] = fmaxf(mrow[r], __shfl_xor(mrow[r], off));
        float psum[4] = {0.f, 0.f, 0.f, 0.f};
        #pragma unroll
        for (int kt = 0; kt < 19; ++kt)
            #pragma unroll
            for (int r = 0; r < 4; ++r) {
                float pcur = __expf(S[kt][r] - mrow[r]);
                S[kt][r] = pcur;
                psum[r] += pcur;
            }
        #pragma unroll
        for (int r = 0; r < 4; ++r)
            #pragma unroll
            for (int off = 1; off < 16; off <<= 1)
                psum[r] += __shfl_xor(psum[r], off);
        float linv[4];
        #pragma unroll
        for (int r = 0; r < 4; ++r) linv[r] = 1.f / psum[r];

        unsigned short* pw = Ps + w * (16 * PS_STRIDE);
        #pragma unroll
        for (int kt = 0; kt < 19; ++kt)
            #pragma unroll
            for (int r = 0; r < 4; ++r)
                pw[(quad * 4 + r) * PS_STRIDE + kt * 16 + l16] = f2bf(S[kt][r]);

        f32x4 o0, o1;
        #pragma unroll
        for (int r = 0; r < 4; ++r) { o0[r] = 0.f; o1[r] = 0.f; }
        #pragma unroll
        for (int ks = 0; ks < 10; ++ks) {
            bf16x8 ap = *(const bf16x8*)(pw + l16 * PS_STRIDE + ks * 32 + quad * 8);
            bf16x8 b0 = *(const bf16x8*)(Vs + l16 * PS_STRIDE + ks * 32 + quad * 8);
            bf16x8 b1 = *(const bf16x8*)(Vs + (16 + l16) * PS_STRIDE + ks * 32 + quad * 8);
            o0 = __builtin_amdgcn_mfma_f32_16x16x32_bf16(ap, b0, o0, 0, 0, 0);
            o1 = __builtin_amdgcn_mfma_f32_16x16x32_bf16(ap, b1, o1, 0, 0, 0);
        }
        #pragma unroll
        for (int r = 0; r < 4; ++r) {
            int q = qt * 16 + quad * 4 + r;
            if (q < LQ_) {
                size_t ob = ((size_t)b * LQ_ + q) * D_ + h * HD_;
                out[ob + l16]      = f2bf(o0[r] * linv[r]);
                out[ob + 16 + l16] = f2bf(o1[r] * linv[r]);
            }
        }
    }
}

// ---------------------------------------------------------------------------
// Deformable sampling. 16 lanes per (b,q,h); lane = 2 channels (dword loads).
// Per-gid uniform params (awl/off/ref) staged to LDS coalesced once per block
// (was: 42 redundant scalar VMEM loads repeated by all 16 lanes of a group).
// Block = 16 gids = 2 consecutive bq x 8 heads.
// ---------------------------------------------------------------------------
__global__ __launch_bounds__(256)
void deform_kernel(const unsigned short* __restrict__ value,
                   const float* __restrict__ off,
                   const float* __restrict__ awl,
                   const float* __restrict__ ref,
                   unsigned short* __restrict__ out) {
    const int lvl_hw[3]    = {80, 40, 20};
    const int lvl_start[3] = {0, 6400, 8000};
    __shared__ float offL[2][192];
    __shared__ float awlL[2][96];
    __shared__ float refL[2][6];

    const int tid = threadIdx.x;
    const int bq0 = blockIdx.x * 2;
    // coalesced stage: 384 + 192 floats as float4, 12 floats scalar
    if (tid < 96)
        ((float4*)&offL[0][0])[tid] = ((const float4*)(off + (size_t)bq0 * 192))[tid];
    else if (tid < 144)
        ((float4*)&awlL[0][0])[tid - 96] = ((const float4*)(awl + (size_t)bq0 * 96))[tid - 96];
    else if (tid < 156)
        (&refL[0][0])[tid - 144] = (ref + (size_t)bq0 * 6)[tid - 144];
    __syncthreads();

    const int g16 = tid >> 4;              // 0..15
    const int c2  = (tid & 15) * 2;
    const int lb  = g16 >> 3;              // local bq (0/1)
    const int h   = g16 & 7;
    const int bq  = bq0 + lb;
    const int b   = bq / LQ_;

    float lg[12];
    float m = -1e30f;
    #pragma unroll
    for (int j = 0; j < 12; ++j) { lg[j] = awlL[lb][h * 12 + j]; m = fmaxf(m, lg[j]); }
    float s = 0.f;
    #pragma unroll
    for (int j = 0; j < 12; ++j) { lg[j] = __expf(lg[j] - m); s += lg[j]; }
    const float inv = 1.0f / s;

    const float* op = &offL[lb][h * 24];
    const float* rp = &refL[lb][0];

    float accx = 0.f, accy = 0.f;
    #pragma unroll
    for (int l = 0; l < NL_; ++l) {
        const int W = lvl_hw[l], H = lvl_hw[l];
        const float fw = (float)W, fh = (float)H;
        const float rx = rp[l * 2 + 0], ry = rp[l * 2 + 1];
        const unsigned short* vbase =
            value + ((size_t)b * LV_ + lvl_start[l]) * D_ + h * HD_ + c2;
        #pragma unroll
        for (int p = 0; p < NP_4; ++p) {
            float ox = op[(l * 4 + p) * 2 + 0], oy = op[(l * 4 + p) * 2 + 1];
            float x = (rx + ox / fw) * fw - 0.5f;
            float y = (ry + oy / fh) * fh - 0.5f;
            float x0f = floorf(x), y0f = floorf(y);
            float wx = x - x0f, wy = y - y0f;
            int x0 = (int)x0f, y0 = (int)y0f;
            float a = lg[l * 4 + p] * inv;
            const float cw[4] = {a * (1.f - wx) * (1.f - wy), a * wx * (1.f - wy),
                                 a * (1.f - wx) * wy,         a * wx * wy};
            const int cx[4] = {x0, x0 + 1, x0,     x0 + 1};
            const int cy[4] = {y0, y0,     y0 + 1, y0 + 1};
            #pragma unroll
            for (int cor = 0; cor < 4; ++cor) {
                int xi = cx[cor], yi = cy[cor];
                if (xi < 0 || xi >= W || yi < 0 || yi >= H) continue;
                unsigned v = *(const unsigned*)(vbase + (size_t)(yi * W + xi) * D_);
                accx += cw[cor] * bf2f((unsigned short)(v & 0xFFFFu));
                accy += cw[cor] * bf2f((unsigned short)(v >> 16));
            }
        }
    }
    unsigned pack = (unsigned)f2bf(accx) | ((unsigned)f2bf(accy) << 16);
    *(unsigned*)(out + (size_t)bq * D_ + h * HD_ + c2) = pack;
}

// ---------------------------------------------------------------------------
// Launch
// ---------------------------------------------------------------------------
extern "C" void kernel_launch(void* const* d_in, const int* in_sizes, int n_in,
                              void* d_out, int out_size, void* d_ws, size_t ws_size,
                              hipStream_t stream) {
    const float* tgt   = (const float*)d_in[0];
    const float* refpt = (const float*)d_in[1];
    const float* mem   = (const float*)d_in[2];
    const float* qpos  = (const float*)d_in[3];
    const float* Wq = (const float*)d_in[6],  *bq = (const float*)d_in[7];
    const float* Wk = (const float*)d_in[8],  *bk = (const float*)d_in[9];
    const float* Wv = (const float*)d_in[10], *bv = (const float*)d_in[11];
    const float* Wo = (const float*)d_in[12], *bo = (const float*)d_in[13];
    const float* ln1_g = (const float*)d_in[14], *ln1_b = (const float*)d_in[15];
    const float* W_vproj = (const float*)d_in[16], *b_vproj = (const float*)d_in[17];
    const float* W_off  = (const float*)d_in[18], *b_off  = (const float*)d_in[19];
    const float* W_attn = (const float*)d_in[20], *b_attn = (const float*)d_in[21];
    const float* W_out  = (const float*)d_in[22], *b_out  = (const float*)d_in[23];
    const float* ln2_g = (const float*)d_in[24], *ln2_b = (const float*)d_in[25];
    const float* W1 = (const float*)d_in[26], *b1 = (const float*)d_in[27];
    const float* W2 = (const float*)d_in[28], *b2 = (const float*)d_in[29];
    const float* ln3_g = (const float*)d_in[30], *ln3_b = (const float*)d_in[31];
    float* out = (float*)d_out;

    // ---- workspace layout ----
    char* p = (char*)d_ws;
    const size_t TOKD = (size_t)NTOK * D_;
    float* buf_attn = (float*)p; p += TOKD * 4;   // used as bf16 (attn/deform out)
    float* buf_tmp  = (float*)p; p += TOKD * 4;   // (spare)
    float* buf_t1   = (float*)p; p += TOKD * 4;
    float* buf_t2   = (float*)p; p += TOKD * 4;
    unsigned short* buf_qh = (unsigned short*)p; p += TOKD * 2;
    unsigned short* buf_kh = (unsigned short*)p; p += TOKD * 2;
    unsigned short* buf_vh = (unsigned short*)p; p += TOKD * 2;
    float* buf_off  = (float*)p; p += (size_t)NTOK * 192 * 4;
    float* buf_awl  = (float*)p; p += (size_t)NTOK * 96 * 4;
    unsigned short* wt_q   = (unsigned short*)p; p += 65536 * 2;
    unsigned short* wt_k   = (unsigned short*)p; p += 65536 * 2;
    unsigned short* wt_v   = (unsigned short*)p; p += 65536 * 2;
    unsigned short* wt_o   = (unsigned short*)p; p += 65536 * 2;
    unsigned short* wt_vp  = (unsigned short*)p; p += 65536 * 2;
    unsigned short* wt_off = (unsigned short*)p; p += 49152 * 2;
    unsigned short* wt_awl = (unsigned short*)p; p += 24576 * 2;
    unsigned short* wt_out = (unsigned short*)p; p += 65536 * 2;
    unsigned short* wt_1   = (unsigned short*)p; p += (size_t)262144 * 2;
    unsigned short* wt_2   = (unsigned short*)p; p += (size_t)262144 * 2;
    unsigned short* buf_value = (unsigned short*)p;      // NVAL*256 bf16
    unsigned short* buf_ffnb  = (unsigned short*)p;      // aliases value (dead by FFN)

    // ---- weight transposes ----
    TrPack pk;
    pk.d[0] = {Wq,      wt_q,   256, 256};
    pk.d[1] = {Wk,      wt_k,   256, 256};
    pk.d[2] = {Wv,      wt_v,   256, 256};
    pk.d[3] = {Wo,      wt_o,   256, 256};
    pk.d[4] = {W_vproj, wt_vp,  256, 256};
    pk.d[5] = {W_off,   wt_off, 256, 192};
    pk.d[6] = {W_attn,  wt_awl, 256, 96};
    pk.d[7] = {W_out,   wt_out, 256, 256};
    pk.d[8] = {W1,      wt_1,   256, 1024};
    pk.d[9] = {W2,      wt_2,   1024, 256};
    tr_kernel<<<dim3(32, 32, 10), 256, 0, stream>>>(pk);

    // --- self attention: Q,K,V in ONE batched launch (1800 blocks) ---
    GPack3 qkv;
    qkv.d[0] = {tgt, qpos,    wt_q, bq, buf_qh, 256};
    qkv.d[1] = {tgt, qpos,    wt_k, bk, buf_kh, 256};
    qkv.d[2] = {tgt, nullptr, wt_v, bv, buf_vh, 256};
    gemm_osb<32, 128, 256, 128, 1, 4, 2><<<dim3(2, NTOK / 32, 3), 256, 0, stream>>>(qkv);
    attn_mfma<<<BS_ * NH_ * 2, 256, 0, stream>>>(buf_qh, buf_kh, buf_vh,
                                                 (unsigned short*)buf_attn);
    // Wo GEMM + residual + LN1 fused
    gemm_ln<256, 128><<<NTOK / 32, 256, 0, stream>>>(
        (const unsigned short*)buf_attn, wt_o, bo, tgt, ln1_g, ln1_b, buf_t1);

    // --- deformable cross attention ---
    // vproj: round-3 proven 64x128 KC=128 config + PF register prefetch of
    // chunk 1 (T14): stage latency hides under chunk-0 MFMAs.
    gemm_os<64, 128, 256, 128, 2, 2, 0, 2, 1><<<dim3(2, NVAL / 64), 256, 0, stream>>>(
        mem, wt_vp, b_vproj, buf_value, NVAL, 256);
    // off + awl in ONE batched launch
    GPack3 oa;
    oa.d[0] = {buf_t1, qpos, wt_off, b_off,  buf_off, 192};
    oa.d[1] = {buf_t1, qpos, wt_awl, b_attn, buf_awl, 96};
    oa.d[2] = oa.d[1];
    gemm_osb<32, 96, 256, 128, 2, 2, 0><<<dim3(2, NTOK / 32, 2), 256, 0, stream>>>(oa);
    deform_kernel<<<NTOK / 2, 256, 0, stream>>>(
        buf_value, buf_off, buf_awl, refpt, (unsigned short*)buf_attn);
    // Wout GEMM + residual + LN2 fused
    gemm_ln<256, 128><<<NTOK / 32, 256, 0, stream>>>(
        (const unsigned short*)buf_attn, wt_out, b_out, buf_t1, ln2_g, ln2_b, buf_t2);

    // --- FFN ---
    gemm_os<32, 128, 256, 128, 1, 4, 0, 3, 1><<<dim3(8, NTOK / 32), 256, 0, stream>>>(
        buf_t2, wt_1, b1, buf_ffnb, NTOK, DFF_);
    // FFN2 + residual + LN3 fused, writes final output
    gemm_ln<1024, 128><<<NTOK / 32, 256, 0, stream>>>(
        buf_ffnb, wt_2, b2, buf_t2, ln3_g, ln3_b, out);
}

// Round 7
// 671.471 us; speedup vs baseline: 1.1730x; 1.1730x over previous
//
#include <hip/hip_runtime.h>
#include <hip/hip_bf16.h>

// Problem constants
#define D_      256
#define NH_     8
#define HD_     32
#define NL_     3
#define NP_4    4
#define BS_     32
#define LQ_     300
#define LV_     8400
#define DFF_    1024
#define NTOK    (BS_ * LQ_)        // 9600
#define NVAL    (BS_ * LV_)        // 268800

typedef __attribute__((ext_vector_type(8))) short bf16x8;
typedef __attribute__((ext_vector_type(4))) float f32x4;

__device__ inline unsigned short f2bf(float x) {
    union { float f; unsigned u; } v; v.f = x;
    unsigned r = v.u + 0x7FFFu + ((v.u >> 16) & 1u);
    return (unsigned short)(r >> 16);
}
__device__ inline float bf2f(unsigned short x) {
    union { unsigned u; float f; } v; v.u = ((unsigned)x) << 16;
    return v.f;
}

// ---------------------------------------------------------------------------
// Weight transpose+convert: Wt[n][k] = bf16(W[k][n]). 10 weights, one launch.
// ---------------------------------------------------------------------------
struct TrDesc { const float* W; unsigned short* Wt; int K; int N; };
struct TrPack { TrDesc d[10]; };

__global__ __launch_bounds__(256)
void tr_kernel(TrPack p) {
    TrDesc d = p.d[blockIdx.z];
    const int n0 = blockIdx.x * 32, k0 = blockIdx.y * 32;
    if (n0 >= d.N || k0 >= d.K) return;
    __shared__ float t[32][33];
    const int tx = threadIdx.x & 31, ty = threadIdx.x >> 5;
    #pragma unroll
    for (int i = 0; i < 4; ++i) {
        int k = k0 + ty + i * 8, n = n0 + tx;
        t[ty + i * 8][tx] = (k < d.K && n < d.N) ? d.W[(size_t)k * d.N + n] : 0.f;
    }
    __syncthreads();
    #pragma unroll
    for (int i = 0; i < 4; ++i) {
        int n = n0 + ty + i * 8, k = k0 + tx;
        if (n < d.N && k < d.K) d.Wt[(size_t)n * d.K + k] = f2bf(t[tx][ty + i * 8]);
    }
}

// ---------------------------------------------------------------------------
// Chunked whole-K LDS GEMM. KC=128 (NC=2): the measured-best phase structure
// (round 2: KC=64 regressed; round 5: reg-streaming regressed; round 6: T14
// register prefetch spilled to scratch under the 128-VGPR cap -> WRITE_SIZE
// 134->403 MB. This simple 2-chunk form at VGPR=52 is the local optimum.)
// AMODE: 0 = f32 A, 2 = bf16 A. CMODE: 0 f32, 2 bf16, 3 bf16+relu.
// ---------------------------------------------------------------------------
template <int ROWS, int COLS, int KK, int KC, int WR, int WC, int AMODE, int CMODE>
__global__ __launch_bounds__(256, 4)
void gemm_os(const void* __restrict__ Ain,
             const unsigned short* __restrict__ Wt, const float* __restrict__ bias,
             void* __restrict__ Cout, int M, int N) {
    constexpr int LDK = KC + 8;
    constexpr int NC = KK / KC;
    constexpr int KS = KC / 32;
    constexpr int WROWS = ROWS / WR, WCOLS = COLS / WC;
    constexpr int RT = WROWS / 16, TC = WCOLS / 16;
    __shared__ unsigned short Alds[ROWS * LDK];
    __shared__ unsigned short Blds[COLS * LDK];

    const int tid = threadIdx.x, lane = tid & 63, w = tid >> 6;
    const int quad = lane >> 4, l16 = lane & 15;
    const int wr = w / WC, wc = w % WC;
    const int rowBase = blockIdx.y * ROWS;
    const int colBase = blockIdx.x * COLS;

    f32x4 acc[RT][TC];
    #pragma unroll
    for (int rt = 0; rt < RT; ++rt)
        #pragma unroll
        for (int j = 0; j < TC; ++j)
            #pragma unroll
            for (int r = 0; r < 4; ++r) acc[rt][j][r] = 0.f;

    for (int ch = 0; ch < NC; ++ch) {
        if (NC > 1 && ch > 0) __syncthreads();
        // ---- stage A chunk ----
        if (AMODE == 2) {
            constexpr int CNT2 = ROWS * KC / 2048;
            #pragma unroll
            for (int i = 0; i < CNT2; ++i) {
                int idx = i * 256 + tid;
                int row = idx / (KC / 8), kofs = (idx % (KC / 8)) * 8;
                int4 v = *(const int4*)((const unsigned short*)Ain +
                          (size_t)(rowBase + row) * KK + ch * KC + kofs);
                *(int4*)&Alds[row * LDK + kofs] = v;
            }
        } else {
            constexpr int CNT = ROWS * KC / 1024;
            #pragma unroll
            for (int i = 0; i < CNT; ++i) {
                int idx = i * 256 + tid;
                int row = idx / (KC / 4), kofs = (idx % (KC / 4)) * 4;
                size_t gg = (size_t)(rowBase + row) * KK + ch * KC + kofs;
                float4 a = *(const float4*)((const float*)Ain + gg);
                ushort4 s4;
                s4.x = f2bf(a.x); s4.y = f2bf(a.y);
                s4.z = f2bf(a.z); s4.w = f2bf(a.w);
                *(ushort4*)&Alds[row * LDK + kofs] = s4;
            }
        }
        // ---- stage B chunk ----
        {
            constexpr int CNT = COLS * KC / 2048;
            #pragma unroll
            for (int i = 0; i < CNT; ++i) {
                int idx = i * 256 + tid;
                int col = idx / (KC / 8), kofs = (idx % (KC / 8)) * 8;
                int4 v = *(const int4*)(Wt + (size_t)(colBase + col) * KK + ch * KC + kofs);
                *(int4*)&Blds[col * LDK + kofs] = v;
            }
        }
        __syncthreads();

        #pragma unroll
        for (int s = 0; s < KS; ++s) {
            bf16x8 af[RT], bfr[TC];
            #pragma unroll
            for (int rt = 0; rt < RT; ++rt)
                af[rt] = *(const bf16x8*)&Alds[(wr * WROWS + rt * 16 + l16) * LDK + s * 32 + quad * 8];
            #pragma unroll
            for (int j = 0; j < TC; ++j)
                bfr[j] = *(const bf16x8*)&Blds[(wc * WCOLS + j * 16 + l16) * LDK + s * 32 + quad * 8];
            #pragma unroll
            for (int rt = 0; rt < RT; ++rt)
                #pragma unroll
                for (int j = 0; j < TC; ++j)
                    acc[rt][j] = __builtin_amdgcn_mfma_f32_16x16x32_bf16(af[rt], bfr[j], acc[rt][j], 0, 0, 0);
        }
    }

    // ---- epilogue ----
    #pragma unroll
    for (int rt = 0; rt < RT; ++rt) {
        #pragma unroll
        for (int j = 0; j < TC; ++j) {
            int col = colBase + wc * WCOLS + j * 16 + l16;
            float bb = bias[col];
            #pragma unroll
            for (int r = 0; r < 4; ++r) {
                int row = rowBase + wr * WROWS + rt * 16 + quad * 4 + r;
                float c = acc[rt][j][r] + bb;
                if (CMODE == 3) c = fmaxf(c, 0.f);
                if (CMODE >= 2)
                    ((unsigned short*)Cout)[(size_t)row * N + col] = f2bf(c);
                else
                    ((float*)Cout)[(size_t)row * N + col] = c;
            }
        }
    }
}

// ---------------------------------------------------------------------------
// Batched GEMM: blockIdx.z selects an independent sub-problem (Q/K/V in one
// launch; off+awl in one launch). A is f32 with optional fused A2 add.
// ---------------------------------------------------------------------------
struct GDesc { const float* Ain; const float* A2; const unsigned short* Wt;
               const float* bias; void* Cout; int N; };
struct GPack3 { GDesc d[3]; };

template <int ROWS, int COLS, int KK, int KC, int WR, int WC, int CMODE>
__global__ __launch_bounds__(256, 4)
void gemm_osb(GPack3 pk) {
    constexpr int LDK = KC + 8;
    constexpr int NC = KK / KC;
    constexpr int KS = KC / 32;
    constexpr int WROWS = ROWS / WR, WCOLS = COLS / WC;
    constexpr int RT = WROWS / 16, TC = WCOLS / 16;
    __shared__ unsigned short Alds[ROWS * LDK];
    __shared__ unsigned short Blds[COLS * LDK];

    GDesc g = pk.d[blockIdx.z];
    const int colBase = blockIdx.x * COLS;
    if (colBase >= g.N) return;
    const int tid = threadIdx.x, lane = tid & 63, w = tid >> 6;
    const int quad = lane >> 4, l16 = lane & 15;
    const int wr = w / WC, wc = w % WC;
    const int rowBase = blockIdx.y * ROWS;

    f32x4 acc[RT][TC];
    #pragma unroll
    for (int rt = 0; rt < RT; ++rt)
        #pragma unroll
        for (int j = 0; j < TC; ++j)
            #pragma unroll
            for (int r = 0; r < 4; ++r) acc[rt][j][r] = 0.f;

    for (int ch = 0; ch < NC; ++ch) {
        if (NC > 1 && ch > 0) __syncthreads();
        {
            constexpr int CNT = ROWS * KC / 1024;
            #pragma unroll
            for (int i = 0; i < CNT; ++i) {
                int idx = i * 256 + tid;
                int row = idx / (KC / 4), kofs = (idx % (KC / 4)) * 4;
                size_t gg = (size_t)(rowBase + row) * KK + ch * KC + kofs;
                float4 a = *(const float4*)(g.Ain + gg);
                if (g.A2) {
                    float4 b = *(const float4*)(g.A2 + gg);
                    a.x += b.x; a.y += b.y; a.z += b.z; a.w += b.w;
                }
                ushort4 s4;
                s4.x = f2bf(a.x); s4.y = f2bf(a.y);
                s4.z = f2bf(a.z); s4.w = f2bf(a.w);
                *(ushort4*)&Alds[row * LDK + kofs] = s4;
            }
        }
        {
            constexpr int CNT = COLS * KC / 2048;
            #pragma unroll
            for (int i = 0; i < CNT; ++i) {
                int idx = i * 256 + tid;
                int col = idx / (KC / 8), kofs = (idx % (KC / 8)) * 8;
                int4 v = *(const int4*)(g.Wt + (size_t)(colBase + col) * KK + ch * KC + kofs);
                *(int4*)&Blds[col * LDK + kofs] = v;
            }
        }
        __syncthreads();

        #pragma unroll
        for (int s = 0; s < KS; ++s) {
            bf16x8 af[RT], bfr[TC];
            #pragma unroll
            for (int rt = 0; rt < RT; ++rt)
                af[rt] = *(const bf16x8*)&Alds[(wr * WROWS + rt * 16 + l16) * LDK + s * 32 + quad * 8];
            #pragma unroll
            for (int j = 0; j < TC; ++j)
                bfr[j] = *(const bf16x8*)&Blds[(wc * WCOLS + j * 16 + l16) * LDK + s * 32 + quad * 8];
            #pragma unroll
            for (int rt = 0; rt < RT; ++rt)
                #pragma unroll
                for (int j = 0; j < TC; ++j)
                    acc[rt][j] = __builtin_amdgcn_mfma_f32_16x16x32_bf16(af[rt], bfr[j], acc[rt][j], 0, 0, 0);
        }
    }

    #pragma unroll
    for (int rt = 0; rt < RT; ++rt) {
        #pragma unroll
        for (int j = 0; j < TC; ++j) {
            int col = colBase + wc * WCOLS + j * 16 + l16;
            float bb = g.bias[col];
            #pragma unroll
            for (int r = 0; r < 4; ++r) {
                int row = rowBase + wr * WROWS + rt * 16 + quad * 4 + r;
                float c = acc[rt][j][r] + bb;
                if (CMODE >= 2)
                    ((unsigned short*)g.Cout)[(size_t)row * g.N + col] = f2bf(c);
                else
                    ((float*)g.Cout)[(size_t)row * g.N + col] = c;
            }
        }
    }
}

// ---------------------------------------------------------------------------
// GEMM (bf16 A, full-row COLS=256) with fused residual-add + LayerNorm.
// out = LN(xres + A@Wt + bias) * lng + lnb.
// ---------------------------------------------------------------------------
template <int KK, int KC>
__global__ __launch_bounds__(256)
void gemm_ln(const unsigned short* __restrict__ Ain,
             const unsigned short* __restrict__ Wt, const float* __restrict__ bias,
             const float* __restrict__ xres, const float* __restrict__ lng,
             const float* __restrict__ lnb, float* __restrict__ Cout) {
    constexpr int ROWS = 32, COLS = 256;
    constexpr int LDK = KC + 8;
    constexpr int NC = KK / KC;
    constexpr int KS = KC / 32;
    constexpr int RT = 2, TC = 4;
    __shared__ unsigned short Alds[ROWS * LDK];
    __shared__ unsigned short Blds[COLS * LDK];
    __shared__ float redS[4][32];
    __shared__ float redQ[4][32];

    const int tid = threadIdx.x, lane = tid & 63, w = tid >> 6;
    const int quad = lane >> 4, l16 = lane & 15;
    const int wc = w;
    const int rowBase = blockIdx.x * ROWS;

    f32x4 acc[RT][TC];
    #pragma unroll
    for (int rt = 0; rt < RT; ++rt)
        #pragma unroll
        for (int j = 0; j < TC; ++j)
            #pragma unroll
            for (int r = 0; r < 4; ++r) acc[rt][j][r] = 0.f;

    for (int ch = 0; ch < NC; ++ch) {
        if (NC > 1 && ch > 0) __syncthreads();
        {
            constexpr int CNT2 = ROWS * KC / 2048;
            #pragma unroll
            for (int i = 0; i < CNT2; ++i) {
                int idx = i * 256 + tid;
                int row = idx / (KC / 8), kofs = (idx % (KC / 8)) * 8;
                int4 v = *(const int4*)(Ain + (size_t)(rowBase + row) * KK + ch * KC + kofs);
                *(int4*)&Alds[row * LDK + kofs] = v;
            }
        }
        {
            constexpr int CNT = COLS * KC / 2048;
            #pragma unroll
            for (int i = 0; i < CNT; ++i) {
                int idx = i * 256 + tid;
                int col = idx / (KC / 8), kofs = (idx % (KC / 8)) * 8;
                int4 v = *(const int4*)(Wt + (size_t)col * KK + ch * KC + kofs);
                *(int4*)&Blds[col * LDK + kofs] = v;
            }
        }
        __syncthreads();

        #pragma unroll
        for (int s = 0; s < KS; ++s) {
            bf16x8 af[RT], bfr[TC];
            #pragma unroll
            for (int rt = 0; rt < RT; ++rt)
                af[rt] = *(const bf16x8*)&Alds[(rt * 16 + l16) * LDK + s * 32 + quad * 8];
            #pragma unroll
            for (int j = 0; j < TC; ++j)
                bfr[j] = *(const bf16x8*)&Blds[(wc * 64 + j * 16 + l16) * LDK + s * 32 + quad * 8];
            #pragma unroll
            for (int rt = 0; rt < RT; ++rt)
                #pragma unroll
                for (int j = 0; j < TC; ++j)
                    acc[rt][j] = __builtin_amdgcn_mfma_f32_16x16x32_bf16(af[rt], bfr[j], acc[rt][j], 0, 0, 0);
        }
    }

    float p[RT][4], q[RT][4];
    #pragma unroll
    for (int rt = 0; rt < RT; ++rt)
        #pragma unroll
        for (int r = 0; r < 4; ++r) { p[rt][r] = 0.f; q[rt][r] = 0.f; }

    #pragma unroll
    for (int rt = 0; rt < RT; ++rt) {
        #pragma unroll
        for (int j = 0; j < TC; ++j) {
            int col = wc * 64 + j * 16 + l16;
            float bb = bias[col];
            #pragma unroll
            for (int r = 0; r < 4; ++r) {
                int row = rowBase + rt * 16 + quad * 4 + r;
                float v = acc[rt][j][r] + bb + xres[(size_t)row * 256 + col];
                acc[rt][j][r] = v;
                p[rt][r] += v;
                q[rt][r] += v * v;
            }
        }
    }
    #pragma unroll
    for (int rt = 0; rt < RT; ++rt)
        #pragma unroll
        for (int r = 0; r < 4; ++r)
            #pragma unroll
            for (int off = 1; off < 16; off <<= 1) {
                p[rt][r] += __shfl_xor(p[rt][r], off);
                q[rt][r] += __shfl_xor(q[rt][r], off);
            }
    if (l16 == 0) {
        #pragma unroll
        for (int rt = 0; rt < RT; ++rt)
            #pragma unroll
            for (int r = 0; r < 4; ++r) {
                redS[w][rt * 16 + quad * 4 + r] = p[rt][r];
                redQ[w][rt * 16 + quad * 4 + r] = q[rt][r];
            }
    }
    __syncthreads();
    #pragma unroll
    for (int rt = 0; rt < RT; ++rt) {
        #pragma unroll
        for (int r = 0; r < 4; ++r) {
            int ridx = rt * 16 + quad * 4 + r;
            float s  = redS[0][ridx] + redS[1][ridx] + redS[2][ridx] + redS[3][ridx];
            float ss = redQ[0][ridx] + redQ[1][ridx] + redQ[2][ridx] + redQ[3][ridx];
            float mean = s * (1.0f / 256.0f);
            float var  = ss * (1.0f / 256.0f) - mean * mean;
            float inv  = rsqrtf(var + 1e-5f);
            int row = rowBase + ridx;
            #pragma unroll
            for (int j = 0; j < TC; ++j) {
                int col = wc * 64 + j * 16 + l16;
                Cout[(size_t)row * 256 + col] =
                    (acc[rt][j][r] - mean) * inv * lng[col] + lnb[col];
            }
        }
    }
}

// ---------------------------------------------------------------------------
// Flash-style MFMA self-attention. Block = (b, h, half); 512 blocks.
// ---------------------------------------------------------------------------
#define PS_STRIDE 344
__global__ __launch_bounds__(256)
void attn_mfma(const unsigned short* __restrict__ qh,
               const unsigned short* __restrict__ kh,
               const unsigned short* __restrict__ vh,
               unsigned short* __restrict__ out) {
    __shared__ unsigned short Ps[4 * 16 * PS_STRIDE];
    __shared__ unsigned short Vs[32 * PS_STRIDE];
    const int tid = threadIdx.x;
    const int bh = blockIdx.x >> 1, half_ = blockIdx.x & 1;
    const int b = bh >> 3, h = bh & 7;
    const int w = tid >> 6, lane = tid & 63;
    const int quad = lane >> 4, l16 = lane & 15;

    for (int i = tid; i < 4 * 16 * PS_STRIDE / 2; i += 256) ((unsigned*)Ps)[i] = 0u;

    const size_t hbase = ((size_t)b * LQ_) * D_ + h * HD_;
    for (int it = 0; it < 10; ++it) {
        int chunk = tid + 256 * it;
        int key = chunk >> 3, cc = (chunk & 7) * 4;
        ushort4 v = make_ushort4(0, 0, 0, 0);
        if (key < LQ_) v = *(const ushort4*)(vh + hbase + (size_t)key * D_ + cc);
        Vs[(cc + 0) * PS_STRIDE + key] = v.x;
        Vs[(cc + 1) * PS_STRIDE + key] = v.y;
        Vs[(cc + 2) * PS_STRIDE + key] = v.z;
        Vs[(cc + 3) * PS_STRIDE + key] = v.w;
    }
    __syncthreads();

    const unsigned short* qb = qh + hbase;
    const unsigned short* kb = kh + hbase;
    const float scale = 0.17677669529663687f;

    for (int qt = 10 * half_ + w; qt < 10 * half_ + 10 && qt < 19; qt += 4) {
        int rowq = qt * 16 + l16; if (rowq > LQ_ - 1) rowq = LQ_ - 1;
        bf16x8 aq = *(const bf16x8*)(qb + (size_t)rowq * D_ + quad * 8);

        f32x4 S[19];
        #pragma unroll
        for (int kt = 0; kt < 19; ++kt) {
            int rowk = kt * 16 + l16; if (rowk > LQ_ - 1) rowk = LQ_ - 1;
            bf16x8 bk = *(const bf16x8*)(kb + (size_t)rowk * D_ + quad * 8);
            f32x4 z; z[0] = z[1] = z[2] = z[3] = 0.f;
            S[kt] = __builtin_amdgcn_mfma_f32_16x16x32_bf16(aq, bk, z, 0, 0, 0);
        }
        float mrow[4] = {-1e30f, -1e30f, -1e30f, -1e30f};
        #pragma unroll
        for (int kt = 0; kt < 19; ++kt) {
            bool masked = (kt == 18) && (l16 >= 12);
            #pragma unroll
            for (int r = 0; r < 4; ++r) {
                float s = masked ? -1e30f : S[kt][r] * scale;
                S[kt][r] = s;
                mrow[r] = fmaxf(mrow[r], s);
            }
        }
        #pragma unroll
        for (int r = 0; r < 4; ++r)
            #pragma unroll
            for (int off = 1; off < 16; off <<= 1)
                mrow[r] = fmaxf(mrow[r], __shfl_xor(mrow[r], off));
        float psum[4] = {0.f, 0.f, 0.f, 0.f};
        #pragma unroll
        for (int kt = 0; kt < 19; ++kt)
            #pragma unroll
            for (int r = 0; r < 4; ++r) {
                float pcur = __expf(S[kt][r] - mrow[r]);
                S[kt][r] = pcur;
                psum[r] += pcur;
            }
        #pragma unroll
        for (int r = 0; r < 4; ++r)
            #pragma unroll
            for (int off = 1; off < 16; off <<= 1)
                psum[r] += __shfl_xor(psum[r], off);
        float linv[4];
        #pragma unroll
        for (int r = 0; r < 4; ++r) linv[r] = 1.f / psum[r];

        unsigned short* pw = Ps + w * (16 * PS_STRIDE);
        #pragma unroll
        for (int kt = 0; kt < 19; ++kt)
            #pragma unroll
            for (int r = 0; r < 4; ++r)
                pw[(quad * 4 + r) * PS_STRIDE + kt * 16 + l16] = f2bf(S[kt][r]);

        f32x4 o0, o1;
        #pragma unroll
        for (int r = 0; r < 4; ++r) { o0[r] = 0.f; o1[r] = 0.f; }
        #pragma unroll
        for (int ks = 0; ks < 10; ++ks) {
            bf16x8 ap = *(const bf16x8*)(pw + l16 * PS_STRIDE + ks * 32 + quad * 8);
            bf16x8 b0 = *(const bf16x8*)(Vs + l16 * PS_STRIDE + ks * 32 + quad * 8);
            bf16x8 b1 = *(const bf16x8*)(Vs + (16 + l16) * PS_STRIDE + ks * 32 + quad * 8);
            o0 = __builtin_amdgcn_mfma_f32_16x16x32_bf16(ap, b0, o0, 0, 0, 0);
            o1 = __builtin_amdgcn_mfma_f32_16x16x32_bf16(ap, b1, o1, 0, 0, 0);
        }
        #pragma unroll
        for (int r = 0; r < 4; ++r) {
            int q = qt * 16 + quad * 4 + r;
            if (q < LQ_) {
                size_t ob = ((size_t)b * LQ_ + q) * D_ + h * HD_;
                out[ob + l16]      = f2bf(o0[r] * linv[r]);
                out[ob + 16 + l16] = f2bf(o1[r] * linv[r]);
            }
        }
    }
}

// ---------------------------------------------------------------------------
// Deformable sampling. 16 lanes per (b,q,h); lane = 2 channels (dword loads).
// Per-gid uniform params (awl/off/ref) staged to LDS coalesced once per block
// (was: 42 redundant scalar VMEM loads repeated by all 16 lanes of a group).
// Block = 16 gids = 2 consecutive bq x 8 heads.
// ---------------------------------------------------------------------------
__global__ __launch_bounds__(256)
void deform_kernel(const unsigned short* __restrict__ value,
                   const float* __restrict__ off,
                   const float* __restrict__ awl,
                   const float* __restrict__ ref,
                   unsigned short* __restrict__ out) {
    const int lvl_hw[3]    = {80, 40, 20};
    const int lvl_start[3] = {0, 6400, 8000};
    __shared__ float offL[2][192];
    __shared__ float awlL[2][96];
    __shared__ float refL[2][6];

    const int tid = threadIdx.x;
    const int bq0 = blockIdx.x * 2;
    // coalesced stage: 384 + 192 floats as float4, 12 floats scalar
    if (tid < 96)
        ((float4*)&offL[0][0])[tid] = ((const float4*)(off + (size_t)bq0 * 192))[tid];
    else if (tid < 144)
        ((float4*)&awlL[0][0])[tid - 96] = ((const float4*)(awl + (size_t)bq0 * 96))[tid - 96];
    else if (tid < 156)
        (&refL[0][0])[tid - 144] = (ref + (size_t)bq0 * 6)[tid - 144];
    __syncthreads();

    const int g16 = tid >> 4;              // 0..15
    const int c2  = (tid & 15) * 2;
    const int lb  = g16 >> 3;              // local bq (0/1)
    const int h   = g16 & 7;
    const int bq  = bq0 + lb;
    const int b   = bq / LQ_;

    float lg[12];
    float m = -1e30f;
    #pragma unroll
    for (int j = 0; j < 12; ++j) { lg[j] = awlL[lb][h * 12 + j]; m = fmaxf(m, lg[j]); }
    float s = 0.f;
    #pragma unroll
    for (int j = 0; j < 12; ++j) { lg[j] = __expf(lg[j] - m); s += lg[j]; }
    const float inv = 1.0f / s;

    const float* op = &offL[lb][h * 24];
    const float* rp = &refL[lb][0];

    float accx = 0.f, accy = 0.f;
    #pragma unroll
    for (int l = 0; l < NL_; ++l) {
        const int W = lvl_hw[l], H = lvl_hw[l];
        const float fw = (float)W, fh = (float)H;
        const float rx = rp[l * 2 + 0], ry = rp[l * 2 + 1];
        const unsigned short* vbase =
            value + ((size_t)b * LV_ + lvl_start[l]) * D_ + h * HD_ + c2;
        #pragma unroll
        for (int p = 0; p < NP_4; ++p) {
            float ox = op[(l * 4 + p) * 2 + 0], oy = op[(l * 4 + p) * 2 + 1];
            float x = (rx + ox / fw) * fw - 0.5f;
            float y = (ry + oy / fh) * fh - 0.5f;
            float x0f = floorf(x), y0f = floorf(y);
            float wx = x - x0f, wy = y - y0f;
            int x0 = (int)x0f, y0 = (int)y0f;
            float a = lg[l * 4 + p] * inv;
            const float cw[4] = {a * (1.f - wx) * (1.f - wy), a * wx * (1.f - wy),
                                 a * (1.f - wx) * wy,         a * wx * wy};
            const int cx[4] = {x0, x0 + 1, x0,     x0 + 1};
            const int cy[4] = {y0, y0,     y0 + 1, y0 + 1};
            #pragma unroll
            for (int cor = 0; cor < 4; ++cor) {
                int xi = cx[cor], yi = cy[cor];
                if (xi < 0 || xi >= W || yi < 0 || yi >= H) continue;
                unsigned v = *(const unsigned*)(vbase + (size_t)(yi * W + xi) * D_);
                accx += cw[cor] * bf2f((unsigned short)(v & 0xFFFFu));
                accy += cw[cor] * bf2f((unsigned short)(v >> 16));
            }
        }
    }
    unsigned pack = (unsigned)f2bf(accx) | ((unsigned)f2bf(accy) << 16);
    *(unsigned*)(out + (size_t)bq * D_ + h * HD_ + c2) = pack;
}

// ---------------------------------------------------------------------------
// Launch
// ---------------------------------------------------------------------------
extern "C" void kernel_launch(void* const* d_in, const int* in_sizes, int n_in,
                              void* d_out, int out_size, void* d_ws, size_t ws_size,
                              hipStream_t stream) {
    const float* tgt   = (const float*)d_in[0];
    const float* refpt = (const float*)d_in[1];
    const float* mem   = (const float*)d_in[2];
    const float* qpos  = (const float*)d_in[3];
    const float* Wq = (const float*)d_in[6],  *bq = (const float*)d_in[7];
    const float* Wk = (const float*)d_in[8],  *bk = (const float*)d_in[9];
    const float* Wv = (const float*)d_in[10], *bv = (const float*)d_in[11];
    const float* Wo = (const float*)d_in[12], *bo = (const float*)d_in[13];
    const float* ln1_g = (const float*)d_in[14], *ln1_b = (const float*)d_in[15];
    const float* W_vproj = (const float*)d_in[16], *b_vproj = (const float*)d_in[17];
    const float* W_off  = (const float*)d_in[18], *b_off  = (const float*)d_in[19];
    const float* W_attn = (const float*)d_in[20], *b_attn = (const float*)d_in[21];
    const float* W_out  = (const float*)d_in[22], *b_out  = (const float*)d_in[23];
    const float* ln2_g = (const float*)d_in[24], *ln2_b = (const float*)d_in[25];
    const float* W1 = (const float*)d_in[26], *b1 = (const float*)d_in[27];
    const float* W2 = (const float*)d_in[28], *b2 = (const float*)d_in[29];
    const float* ln3_g = (const float*)d_in[30], *ln3_b = (const float*)d_in[31];
    float* out = (float*)d_out;

    // ---- workspace layout ----
    char* p = (char*)d_ws;
    const size_t TOKD = (size_t)NTOK * D_;
    float* buf_attn = (float*)p; p += TOKD * 4;   // used as bf16 (attn/deform out)
    float* buf_tmp  = (float*)p; p += TOKD * 4;   // (spare)
    float* buf_t1   = (float*)p; p += TOKD * 4;
    float* buf_t2   = (float*)p; p += TOKD * 4;
    unsigned short* buf_qh = (unsigned short*)p; p += TOKD * 2;
    unsigned short* buf_kh = (unsigned short*)p; p += TOKD * 2;
    unsigned short* buf_vh = (unsigned short*)p; p += TOKD * 2;
    float* buf_off  = (float*)p; p += (size_t)NTOK * 192 * 4;
    float* buf_awl  = (float*)p; p += (size_t)NTOK * 96 * 4;
    unsigned short* wt_q   = (unsigned short*)p; p += 65536 * 2;
    unsigned short* wt_k   = (unsigned short*)p; p += 65536 * 2;
    unsigned short* wt_v   = (unsigned short*)p; p += 65536 * 2;
    unsigned short* wt_o   = (unsigned short*)p; p += 65536 * 2;
    unsigned short* wt_vp  = (unsigned short*)p; p += 65536 * 2;
    unsigned short* wt_off = (unsigned short*)p; p += 49152 * 2;
    unsigned short* wt_awl = (unsigned short*)p; p += 24576 * 2;
    unsigned short* wt_out = (unsigned short*)p; p += 65536 * 2;
    unsigned short* wt_1   = (unsigned short*)p; p += (size_t)262144 * 2;
    unsigned short* wt_2   = (unsigned short*)p; p += (size_t)262144 * 2;
    unsigned short* buf_value = (unsigned short*)p;      // NVAL*256 bf16
    unsigned short* buf_ffnb  = (unsigned short*)p;      // aliases value (dead by FFN)

    // ---- weight transposes ----
    TrPack pk;
    pk.d[0] = {Wq,      wt_q,   256, 256};
    pk.d[1] = {Wk,      wt_k,   256, 256};
    pk.d[2] = {Wv,      wt_v,   256, 256};
    pk.d[3] = {Wo,      wt_o,   256, 256};
    pk.d[4] = {W_vproj, wt_vp,  256, 256};
    pk.d[5] = {W_off,   wt_off, 256, 192};
    pk.d[6] = {W_attn,  wt_awl, 256, 96};
    pk.d[7] = {W_out,   wt_out, 256, 256};
    pk.d[8] = {W1,      wt_1,   256, 1024};
    pk.d[9] = {W2,      wt_2,   1024, 256};
    tr_kernel<<<dim3(32, 32, 10), 256, 0, stream>>>(pk);

    // --- self attention: Q,K,V in ONE batched launch (1800 blocks) ---
    GPack3 qkv;
    qkv.d[0] = {tgt, qpos,    wt_q, bq, buf_qh, 256};
    qkv.d[1] = {tgt, qpos,    wt_k, bk, buf_kh, 256};
    qkv.d[2] = {tgt, nullptr, wt_v, bv, buf_vh, 256};
    gemm_osb<32, 128, 256, 128, 1, 4, 2><<<dim3(2, NTOK / 32, 3), 256, 0, stream>>>(qkv);
    attn_mfma<<<BS_ * NH_ * 2, 256, 0, stream>>>(buf_qh, buf_kh, buf_vh,
                                                 (unsigned short*)buf_attn);
    // Wo GEMM + residual + LN1 fused
    gemm_ln<256, 128><<<NTOK / 32, 256, 0, stream>>>(
        (const unsigned short*)buf_attn, wt_o, bo, tgt, ln1_g, ln1_b, buf_t1);

    // --- deformable cross attention ---
    // vproj: ROWS=64, KC=128 (NC=2) — the proven config (round 3: 680 µs total).
    gemm_os<64, 128, 256, 128, 2, 2, 0, 2><<<dim3(2, NVAL / 64), 256, 0, stream>>>(
        mem, wt_vp, b_vproj, buf_value, NVAL, 256);
    // off + awl in ONE batched launch
    GPack3 oa;
    oa.d[0] = {buf_t1, qpos, wt_off, b_off,  buf_off, 192};
    oa.d[1] = {buf_t1, qpos, wt_awl, b_attn, buf_awl, 96};
    oa.d[2] = oa.d[1];
    gemm_osb<32, 96, 256, 128, 2, 2, 0><<<dim3(2, NTOK / 32, 2), 256, 0, stream>>>(oa);
    deform_kernel<<<NTOK / 2, 256, 0, stream>>>(
        buf_value, buf_off, buf_awl, refpt, (unsigned short*)buf_attn);
    // Wout GEMM + residual + LN2 fused
    gemm_ln<256, 128><<<NTOK / 32, 256, 0, stream>>>(
        (const unsigned short*)buf_attn, wt_out, b_out, buf_t1, ln2_g, ln2_b, buf_t2);

    // --- FFN ---
    gemm_os<32, 128, 256, 128, 1, 4, 0, 3><<<dim3(8, NTOK / 32), 256, 0, stream>>>(
        buf_t2, wt_1, b1, buf_ffnb, NTOK, DFF_);
    // FFN2 + residual + LN3 fused, writes final output
    gemm_ln<1024, 128><<<NTOK / 32, 256, 0, stream>>>(
        buf_ffnb, wt_2, b2, buf_t2, ln3_g, ln3_b, out);
}